// Round 5
// baseline (206.787 us; speedup 1.0000x reference)
//
#include <hip/hip_runtime.h>

#define B_ 16
#define T_ 4096
#define D_ 128
#define L_ 128
#define NC_ 32            // T_/L_
#define CH_ (B_*NC_)      // 512 chunks
#define LDK 136           // padded bf16 row stride for k1 LDS
#define LDP 136           // padded stride for k3 wave-private P buffer

typedef __attribute__((ext_vector_type(8))) short bf16x8;
typedef __attribute__((ext_vector_type(4))) float f32x4;

__device__ __forceinline__ float clampf(float x, float lo, float hi) {
    return fminf(fmaxf(x, lo), hi);
}
__device__ __forceinline__ float phi_f(float x) {   // elu(x)+1
    return x > 0.f ? x + 1.f : __expf(x);
}
__device__ __forceinline__ unsigned short bf16r(float f) {  // RNE f32->bf16
    unsigned u = __builtin_bit_cast(unsigned, f);
    u += 0x7FFFu + ((u >> 16) & 1u);
    return (unsigned short)(u >> 16);
}
__device__ __forceinline__ float fbf(unsigned short h) {
    unsigned u = ((unsigned)h) << 16; return __builtin_bit_cast(float, u);
}
__device__ __forceinline__ unsigned pack2bf(float a, float b) {
    return (unsigned)bf16r(a) | ((unsigned)bf16r(b) << 16);
}
__device__ __forceinline__ uint4 pack8(const float* f) {
    uint4 r;
    r.x = pack2bf(f[0], f[1]); r.y = pack2bf(f[2], f[3]);
    r.z = pack2bf(f[4], f[5]); r.w = pack2bf(f[6], f[7]);
    return r;
}
__device__ __forceinline__ f32x4 zero4() { f32x4 z; z[0]=0.f; z[1]=0.f; z[2]=0.f; z[3]=0.f; return z; }

// Fragment-tiled index for a 128(row) x 128(k) bf16 matrix (16x16x32 MFMA A-operand):
//   tile(m,ks), lane(lg4*16+l15), j:  elem[row=m*16+l15][k=ks*32+lg4*8+j]
//   flat = ((m*4+ks)*64 + lane)*8 + j       (16 KB per matrix)

// ---------------- K_pre: cum-log decays + frag-tiled bf16 phiK*m and V^T ----------------
__global__ __launch_bounds__(256) void k_pre(
        const float* __restrict__ beta,
        const float* __restrict__ bb1, const float* __restrict__ bb2,
        const float* __restrict__ kk, const float* __restrict__ vv,
        const float* __restrict__ mask,
        float* __restrict__ lg1, float* __restrict__ lg2,
        unsigned short* __restrict__ phiKT, unsigned short* __restrict__ VtT) {
    int ch = blockIdx.x;
    int b = ch / NC_, c = ch % NC_;
    int tbase = b * T_ + c * L_;
    int tid = threadIdx.x;
    size_t cb = (size_t)ch * (D_ * L_);
    __shared__ float s1[L_], s2[L_];
    __shared__ unsigned short sV[32 * 136];

    // --- cumulative log decays (tid<128 active, barriers all) ---
    int t = tid & 127;
    if (tid < 128) {
        float b1b = clampf(1.f / (1.f + __expf(-bb1[0])), 0.01f, 0.995f);
        float b2b = clampf(1.f / (1.f + __expf(-bb2[0])), 0.01f, 0.995f);
        float be = clampf(beta[tbase + t], 0.01f, 0.995f);
        s1[t] = __logf(clampf(b1b * be, 0.01f, 0.995f));
        s2[t] = __logf(clampf(b2b * be, 0.01f, 0.995f));
    }
    __syncthreads();
    for (int off = 1; off < L_; off <<= 1) {
        float a1 = 0.f, a2 = 0.f;
        if (tid < 128 && t >= off) { a1 = s1[t - off]; a2 = s2[t - off]; }
        __syncthreads();
        if (tid < 128) { s1[t] += a1; s2[t] += a2; }
        __syncthreads();
    }
    if (tid < 128) { lg1[tbase + t] = s1[t]; lg2[tbase + t] = s2[t]; }

    // --- phiK*m frag-tiled (thread owns row s, 8 consecutive d -> one octet) ---
#pragma unroll
    for (int p = 0; p < 8; ++p) {
        int i = tid + p * 256;          // 2048 = 128 s x 16 dgrp
        int s = i >> 4, dg = i & 15, d0 = dg * 8;
        const float* kp = &kk[(size_t)(tbase + s) * D_ + d0];
        float4 x0 = *(const float4*)kp;
        float4 x1 = *(const float4*)(kp + 4);
        float m = mask[tbase + s];
        float pq[8] = {phi_f(x0.x)*m, phi_f(x0.y)*m, phi_f(x0.z)*m, phi_f(x0.w)*m,
                       phi_f(x1.x)*m, phi_f(x1.y)*m, phi_f(x1.z)*m, phi_f(x1.w)*m};
        int mt = s >> 4, ks = d0 >> 5, lg4 = (d0 >> 3) & 3, l15 = s & 15;
        *(uint4*)&phiKT[cb + (size_t)(((mt * 4 + ks) * 64 + lg4 * 16 + l15) * 8)] = pack8(pq);
    }

    // --- V^T frag-tiled via 32-s LDS transpose slabs ---
    for (int slab = 0; slab < 4; ++slab) {
        __syncthreads();
#pragma unroll
        for (int p = 0; p < 2; ++p) {
            int i = tid + p * 256;      // 512 = 32 s x 16 egrp
            int sp = i >> 4, eg = i & 15, e0 = eg * 8;
            const float* vp = &vv[(size_t)(tbase + slab * 32 + sp) * D_ + e0];
            float4 x0 = *(const float4*)vp;
            float4 x1 = *(const float4*)(vp + 4);
            float pv8[8] = {x0.x, x0.y, x0.z, x0.w, x1.x, x1.y, x1.z, x1.w};
            *(uint4*)&sV[sp * 136 + e0] = pack8(pv8);
        }
        __syncthreads();
#pragma unroll
        for (int p = 0; p < 2; ++p) {
            int i = tid + p * 256;      // 512 = 8 mg x 64 lane
            int mg = i >> 6, ln = i & 63;
            int lg4 = ln >> 4, l15 = ln & 15;
            unsigned short u[8];
#pragma unroll
            for (int j = 0; j < 8; ++j)
                u[j] = sV[(lg4 * 8 + j) * 136 + mg * 16 + l15];
            uint4 r;
            r.x = (unsigned)u[0] | ((unsigned)u[1] << 16);
            r.y = (unsigned)u[2] | ((unsigned)u[3] << 16);
            r.z = (unsigned)u[4] | ((unsigned)u[5] << 16);
            r.w = (unsigned)u[6] | ((unsigned)u[7] << 16);
            *(uint4*)&VtT[cb + (size_t)(((mg * 4 + slab) * 64 + ln) * 8)] = r;
        }
    }
}

// ---------------- K1: chunk state contribution + zc column sums ----------------
__global__ __launch_bounds__(256) void k1_v5(
        const float* __restrict__ kk, const float* __restrict__ mask,
        const float* __restrict__ lg1, const float* __restrict__ lg2,
        const unsigned short* __restrict__ VtT,
        unsigned short* __restrict__ Cws, float* __restrict__ zc) {
    int ch = blockIdx.x;
    int b = ch / NC_, c = ch % NC_;
    int tbase = b * T_ + c * L_;
    int tid = threadIdx.x, lane = tid & 63, w = tid >> 6;
    int l15 = lane & 15, lg4 = lane >> 4;

    __shared__ unsigned short sK[128 * LDK];   // (w*phiK*m)^T [d][s]
    __shared__ float wL[2][L_];
    __shared__ float sZp[256];

    if (tid < 128) {
        float tot1 = lg1[tbase + L_ - 1], tot2 = lg2[tbase + L_ - 1];
        wL[0][tid] = __expf(tot1 - lg1[tbase + tid]);
        wL[1][tid] = __expf(tot2 - lg2[tbase + tid]);
    }
    __syncthreads();

    const unsigned short* Vch = VtT + (size_t)ch * 16384;

    for (int st = 0; st < 2; ++st) {
#pragma unroll
        for (int p = 0; p < 16; ++p) {
            int i = tid + p * 256;
            int s = i & 127, d4 = i >> 7;
            float4 kq = *(const float4*)&kk[(size_t)(tbase + s) * D_ + d4 * 4];
            float m = mask[tbase + s] * wL[st][s];
            sK[(d4 * 4 + 0) * LDK + s] = bf16r(phi_f(kq.x) * m);
            sK[(d4 * 4 + 1) * LDK + s] = bf16r(phi_f(kq.y) * m);
            sK[(d4 * 4 + 2) * LDK + s] = bf16r(phi_f(kq.z) * m);
            sK[(d4 * 4 + 3) * LDK + s] = bf16r(phi_f(kq.w) * m);
        }
        __syncthreads();

        f32x4 acc[2][8];
#pragma unroll
        for (int m = 0; m < 2; ++m)
#pragma unroll
            for (int n = 0; n < 8; ++n) acc[m][n] = zero4();
#pragma unroll
        for (int ks = 0; ks < 4; ++ks) {
            int koff = ks * 32 + lg4 * 8;
            bf16x8 a0 = *(const bf16x8*)&Vch[(size_t)((((w * 2 + 0) * 4 + ks) * 64 + lane) * 8)];
            bf16x8 a1 = *(const bf16x8*)&Vch[(size_t)((((w * 2 + 1) * 4 + ks) * 64 + lane) * 8)];
#pragma unroll
            for (int n = 0; n < 8; ++n) {
                bf16x8 bb = *(const bf16x8*)&sK[(n * 16 + l15) * LDK + koff];
                acc[0][n] = __builtin_amdgcn_mfma_f32_16x16x32_bf16(a0, bb, acc[0][n], 0, 0, 0);
                acc[1][n] = __builtin_amdgcn_mfma_f32_16x16x32_bf16(a1, bb, acc[1][n], 0, 0, 0);
            }
        }

        // zc column sums from staged sK (256 threads: d = tid&127, half = tid>>7)
        {
            int zd = tid & 127, zh = tid >> 7;
            float zp = 0.f;
#pragma unroll
            for (int i = 0; i < 16; ++i) {
                uint2 u = *(const uint2*)&sK[zd * LDK + zh * 64 + i * 4];
                zp += fbf((unsigned short)(u.x & 0xffff)) + fbf((unsigned short)(u.x >> 16))
                    + fbf((unsigned short)(u.y & 0xffff)) + fbf((unsigned short)(u.y >> 16));
            }
            sZp[tid] = zp;
        }
        __syncthreads();   // sK reads done (MFMA frags + zc), sZp visible
        if (tid < 128)
            zc[((size_t)(st * B_ + b) * NC_ + c) * D_ + tid] = sZp[tid] + sZp[tid + 128];

        unsigned short* Cp = Cws + ((size_t)(st * B_ + b) * NC_ + c) * (D_ * D_);
#pragma unroll
        for (int m = 0; m < 2; ++m)
#pragma unroll
            for (int n = 0; n < 8; ++n)
#pragma unroll
                for (int r = 0; r < 4; ++r) {
                    int e = w * 32 + m * 16 + lg4 * 4 + r;   // row of Ct
                    int d = n * 16 + l15;                    // k-dim
                    int tm = e >> 4, tl = e & 15, tk = d >> 5, tg = (d >> 3) & 3, tj = d & 7;
                    Cp[(size_t)(((tm * 4 + tk) * 64 + tg * 16 + tl) * 8 + tj)] = bf16r(acc[m][n][r]);
                }
    }
}

// ---------------- K2: chunk-state scan, 4 elems/thread ----------------
__global__ void k2_scan(unsigned short* __restrict__ Cws,
                        const float* __restrict__ lg1, const float* __restrict__ lg2) {
    int g = blockIdx.x * blockDim.x + threadIdx.x;   // 131072 = 2*B*D*D/4
    int st = g >> 16;
    int rem = g & 65535;
    int b = rem >> 12;
    int de = (rem & 4095) * 4;
    const float* lg = st ? lg2 : lg1;
    size_t base = ((size_t)(st * B_ + b) * NC_) * (D_ * D_) + de;
    float run0 = 0.f, run1 = 0.f, run2 = 0.f, run3 = 0.f;
    for (int c = 0; c < NC_; c++) {
        float a = __expf(lg[b * T_ + c * L_ + L_ - 1]);
        uint2 val = *(uint2*)&Cws[base + (size_t)c * (D_ * D_)];
        float t0 = fbf((unsigned short)(val.x & 0xffff)), t1 = fbf((unsigned short)(val.x >> 16));
        float t2 = fbf((unsigned short)(val.y & 0xffff)), t3 = fbf((unsigned short)(val.y >> 16));
        uint2 wv; wv.x = pack2bf(run0, run1); wv.y = pack2bf(run2, run3);
        *(uint2*)&Cws[base + (size_t)c * (D_ * D_)] = wv;
        run0 = a * run0 + t0; run1 = a * run1 + t1;
        run2 = a * run2 + t2; run3 = a * run3 + t3;
    }
}

__global__ void k2z_scan(float* __restrict__ zc,
                         const float* __restrict__ lg1, const float* __restrict__ lg2) {
    int g = blockIdx.x * blockDim.x + threadIdx.x;   // 2*B*D
    int st = g / (B_ * D_);
    int rem = g % (B_ * D_);
    int b = rem / D_;
    int d = rem % D_;
    const float* lg = st ? lg2 : lg1;
    size_t base = ((size_t)(st * B_ + b) * NC_) * D_ + d;
    float run = 0.f;
    for (int c = 0; c < NC_; c++) {
        float a = __expf(lg[b * T_ + c * L_ + L_ - 1]);
        float tmp = zc[base + (size_t)c * D_];
        zc[base + (size_t)c * D_] = run;
        run = a * run + tmp;
    }
}

// ---------------- K3 v5: zero-barrier, frag-tiled, e-half split ----------------
template<int HH>
__device__ __forceinline__ void k3_body(
        int ch, int eh,
        const float* __restrict__ qq, const float* __restrict__ mask,
        const float* __restrict__ lg1, const float* __restrict__ lg2,
        const unsigned short* __restrict__ phiKT, const unsigned short* __restrict__ VtT,
        const unsigned short* __restrict__ Cws, const float* __restrict__ zc,
        float* __restrict__ out, unsigned short* bufPw) {
    constexpr int SR = HH ? 128 : 64;   // causal s-range
    constexpr int NS = SR / 16;
    constexpr int KS = SR / 32;
    constexpr int rbase = HH * 64;
    int b = ch / NC_, c = ch % NC_;
    int tbase = b * T_ + c * L_;
    int tid = threadIdx.x, lane = tid & 63;
    int w = tid >> 6, l15 = lane & 15, lg4 = lane >> 4;
    int trow = rbase + w * 16 + l15;
    size_t gt = (size_t)(tbase + trow);
    size_t cb = (size_t)ch * 16384;

    float lg1t = lg1[gt], lg2t = lg2[gt], mt = mask[gt];
    float a1t = __expf(lg1t), a2t = __expf(lg2t);

    // ---- phiQ B-fragments in registers ----
    bf16x8 qf[4];
#pragma unroll
    for (int ks = 0; ks < 4; ++ks) {
        const float* qp = &qq[gt * D_ + ks * 32 + lg4 * 8];
        float4 x0 = *(const float4*)qp;
        float4 x1 = *(const float4*)(qp + 4);
        float pq[8] = {phi_f(x0.x), phi_f(x0.y), phi_f(x0.z), phi_f(x0.w),
                       phi_f(x1.x), phi_f(x1.y), phi_f(x1.z), phi_f(x1.w)};
#pragma unroll
        for (int j = 0; j < 8; ++j) qf[ks][j] = (short)bf16r(pq[j]);
    }

    // ---- S^T = phiK @ phiQ^T (batched A-frag loads), P -> bufP, rowsum ----
    float rs = 0.f;
#pragma unroll
    for (int mh = 0; mh < NS / 4; ++mh) {
        f32x4 accs[4];
#pragma unroll
        for (int m = 0; m < 4; ++m) accs[m] = zero4();
#pragma unroll
        for (int ks = 0; ks < 4; ++ks) {
            bf16x8 kf[4];
#pragma unroll
            for (int m = 0; m < 4; ++m)
                kf[m] = *(const bf16x8*)&phiKT[cb + (size_t)((((mh * 4 + m) * 4 + ks) * 64 + lane) * 8)];
#pragma unroll
            for (int m = 0; m < 4; ++m)
                accs[m] = __builtin_amdgcn_mfma_f32_16x16x32_bf16(kf[m], qf[ks], accs[m], 0, 0, 0);
        }
#pragma unroll
        for (int m = 0; m < 4; ++m) {
            int s0 = (mh * 4 + m) * 16 + lg4 * 4;
            float4 l1s = *(const float4*)&lg1[tbase + s0];
            float4 l2s = *(const float4*)&lg2[tbase + s0];
            float l1a[4] = {l1s.x, l1s.y, l1s.z, l1s.w};
            float l2a[4] = {l2s.x, l2s.y, l2s.z, l2s.w};
            float pv[4];
#pragma unroll
            for (int r = 0; r < 4; ++r) {
                int s = s0 + r;
                float p = 0.f;
                if (s <= trow)
                    p = accs[m][r] * (__expf(lg1t - l1a[r]) + __expf(lg2t - l2a[r]));
                pv[r] = p; rs += p;
            }
            uint2 dd;
            dd.x = pack2bf(pv[0], pv[1]);
            dd.y = pack2bf(pv[2], pv[3]);
            *(uint2*)&bufPw[l15 * LDP + s0] = dd;
        }
    }
    rs += __shfl_xor(rs, 16); rs += __shfl_xor(rs, 32);

    // ---- den inter-chunk: per-lane dot phiQ . Z (from bf16 qf) ----
    const float* z1p = &zc[((size_t)(0 * B_ + b) * NC_ + c) * D_];
    const float* z2p = &zc[((size_t)(1 * B_ + b) * NC_ + c) * D_];
    float d1 = 0.f, d2 = 0.f;
#pragma unroll
    for (int ks = 0; ks < 4; ++ks) {
        int off = ks * 32 + lg4 * 8;
        float4 za = *(const float4*)(z1p + off), zb = *(const float4*)(z1p + off + 4);
        float4 zca = *(const float4*)(z2p + off), zcb = *(const float4*)(z2p + off + 4);
        float z1a[8] = {za.x, za.y, za.z, za.w, zb.x, zb.y, zb.z, zb.w};
        float z2a[8] = {zca.x, zca.y, zca.z, zca.w, zcb.x, zcb.y, zcb.z, zcb.w};
#pragma unroll
        for (int j = 0; j < 8; ++j) {
            float fq = fbf((unsigned short)qf[ks][j]);
            d1 += fq * z1a[j];
            d2 += fq * z2a[j];
        }
    }
    d1 += __shfl_xor(d1, 16); d1 += __shfl_xor(d1, 32);
    d2 += __shfl_xor(d2, 16); d2 += __shfl_xor(d2, 32);
    float osc = mt / fmaxf(a1t * d1 + a2t * d2 + rs, 1e-6f);

    // ---- QH: acc_o^T[e][t] += (a_st*phiQ) . H_st ----
    f32x4 acc_o[4];
#pragma unroll
    for (int m = 0; m < 4; ++m) acc_o[m] = zero4();
#pragma unroll
    for (int st = 0; st < 2; ++st) {
        const unsigned short* Hp = Cws + ((size_t)(st * B_ + b) * NC_ + c) * (D_ * D_);
        float sc = st ? a2t : a1t;
#pragma unroll
        for (int ks = 0; ks < 4; ++ks) {
            bf16x8 hf[4];
#pragma unroll
            for (int m = 0; m < 4; ++m)
                hf[m] = *(const bf16x8*)&Hp[(size_t)((((eh * 4 + m) * 4 + ks) * 64 + lane) * 8)];
            bf16x8 qs;
#pragma unroll
            for (int j = 0; j < 8; ++j)
                qs[j] = (short)bf16r(fbf((unsigned short)qf[ks][j]) * sc);
#pragma unroll
            for (int m = 0; m < 4; ++m)
                acc_o[m] = __builtin_amdgcn_mfma_f32_16x16x32_bf16(hf[m], qs, acc_o[m], 0, 0, 0);
        }
    }

    // ---- PV: acc_o += Vt @ P^T (B re-read by same wave: no barrier) ----
#pragma unroll
    for (int ks = 0; ks < KS; ++ks) {
        bf16x8 pf = *(const bf16x8*)&bufPw[l15 * LDP + ks * 32 + lg4 * 8];
        bf16x8 vf[4];
#pragma unroll
        for (int m = 0; m < 4; ++m)
            vf[m] = *(const bf16x8*)&VtT[cb + (size_t)((((eh * 4 + m) * 4 + ks) * 64 + lane) * 8)];
#pragma unroll
        for (int m = 0; m < 4; ++m)
            acc_o[m] = __builtin_amdgcn_mfma_f32_16x16x32_bf16(vf[m], pf, acc_o[m], 0, 0, 0);
    }

    // ---- store ----
#pragma unroll
    for (int m = 0; m < 4; ++m) {
        float4 o;
        o.x = acc_o[m][0] * osc; o.y = acc_o[m][1] * osc;
        o.z = acc_o[m][2] * osc; o.w = acc_o[m][3] * osc;
        *(float4*)&out[gt * D_ + eh * 64 + m * 16 + lg4 * 4] = o;
    }
}

__global__ __launch_bounds__(256, 6) void k3_v5(
        const float* __restrict__ qq, const float* __restrict__ mask,
        const float* __restrict__ lg1, const float* __restrict__ lg2,
        const unsigned short* __restrict__ phiKT, const unsigned short* __restrict__ VtT,
        const unsigned short* __restrict__ Cws, const float* __restrict__ zc,
        float* __restrict__ out) {
    __shared__ unsigned short bufP[4][16 * LDP];   // wave-private P, 17408 B
    int g = blockIdx.x;                            // 2048 blocks
    int ch = (g & 7) | ((g >> 5) << 3);            // 4 sibling blocks per chunk -> same XCD
    int var = (g >> 3) & 3;
    int eh = var >> 1;
    int w = threadIdx.x >> 6;
    if (var & 1)
        k3_body<1>(ch, eh, qq, mask, lg1, lg2, phiKT, VtT, Cws, zc, out, &bufP[w][0]);
    else
        k3_body<0>(ch, eh, qq, mask, lg1, lg2, phiKT, VtT, Cws, zc, out, &bufP[w][0]);
}

extern "C" void kernel_launch(void* const* d_in, const int* in_sizes, int n_in,
                              void* d_out, int out_size, void* d_ws, size_t ws_size,
                              hipStream_t stream) {
    const float* q    = (const float*)d_in[0];
    const float* k    = (const float*)d_in[1];
    const float* v    = (const float*)d_in[2];
    const float* beta = (const float*)d_in[3];
    const float* mask = (const float*)d_in[4];
    const float* bb1  = (const float*)d_in[5];
    const float* bb2  = (const float*)d_in[6];
    float* out = (float*)d_out;

    size_t n_lg = (size_t)B_ * T_;                       // 65536
    size_t n_z  = (size_t)2 * B_ * NC_ * D_;             // 131072
    size_t n_C  = (size_t)2 * B_ * NC_ * D_ * D_;        // 16777216 bf16
    size_t n_kt = (size_t)B_ * T_ * D_;                  // 8388608 bf16
    size_t need = (2 * n_lg + n_z) * sizeof(float) + (n_C + 2 * n_kt) * sizeof(unsigned short);
    if (ws_size < need) return;

    float* lg1 = (float*)d_ws;
    float* lg2 = lg1 + n_lg;
    float* zc  = lg2 + n_lg;
    unsigned short* Cws   = (unsigned short*)(zc + n_z);
    unsigned short* phiKT = Cws + n_C;
    unsigned short* VtT   = phiKT + n_kt;

    k_pre<<<CH_, 256, 0, stream>>>(beta, bb1, bb2, k, v, mask, lg1, lg2, phiKT, VtT);
    k1_v5<<<CH_, 256, 0, stream>>>(k, mask, lg1, lg2, VtT, Cws, zc);
    k2_scan<<<(2 * B_ * D_ * D_ / 4) / 256, 256, 0, stream>>>(Cws, lg1, lg2);
    k2z_scan<<<(2 * B_ * D_) / 256, 256, 0, stream>>>(zc, lg1, lg2);
    k3_v5<<<4 * CH_, 256, 0, stream>>>(q, mask, lg1, lg2, phiKT, VtT, Cws, zc, out);
}

// Round 6
// 85.092 us; speedup vs baseline: 2.4302x; 2.4302x over previous
//
#include <hip/hip_runtime.h>

#define B_ 16
#define T_ 4096
#define D_ 128
#define L_ 128
#define NC_ 32            // T_/L_
#define CH_ (B_*NC_)      // 512 chunks
#define LDK 136           // padded bf16 row stride (272B)
#define LDP 136

typedef __attribute__((ext_vector_type(8))) short bf16x8;
typedef __attribute__((ext_vector_type(4))) float f32x4;

__device__ __forceinline__ float clampf(float x, float lo, float hi) {
    return fminf(fmaxf(x, lo), hi);
}
__device__ __forceinline__ float phi_f(float x) {   // elu(x)+1
    return x > 0.f ? x + 1.f : __expf(x);
}
__device__ __forceinline__ unsigned short bf16r(float f) {  // RNE f32->bf16
    unsigned u = __builtin_bit_cast(unsigned, f);
    u += 0x7FFFu + ((u >> 16) & 1u);
    return (unsigned short)(u >> 16);
}
__device__ __forceinline__ float fbf(unsigned short h) {
    unsigned u = ((unsigned)h) << 16; return __builtin_bit_cast(float, u);
}
__device__ __forceinline__ unsigned pack2bf(float a, float b) {
    return (unsigned)bf16r(a) | ((unsigned)bf16r(b) << 16);
}
__device__ __forceinline__ uint4 pack8(const float* f) {
    uint4 r;
    r.x = pack2bf(f[0], f[1]); r.y = pack2bf(f[2], f[3]);
    r.z = pack2bf(f[4], f[5]); r.w = pack2bf(f[6], f[7]);
    return r;
}
__device__ __forceinline__ f32x4 zero4() { f32x4 z; z[0]=0.f; z[1]=0.f; z[2]=0.f; z[3]=0.f; return z; }

// Fragment-tiled (A-layout) index for a 128(row) x 128(k) bf16 matrix:
//   flat = ((rowtile*4 + ktile)*64 + (kgrp*16 + row15))*8 + j
//   element [row = rowtile*16 + row15][k = ktile*32 + kgrp*8 + j]

// ================= kA: cumlog + staging + chunk-state GEMM (fused) =================
__global__ __launch_bounds__(256, 2) void kA(
        const float* __restrict__ beta,
        const float* __restrict__ bb1, const float* __restrict__ bb2,
        const float* __restrict__ kk, const float* __restrict__ vv,
        const float* __restrict__ mask,
        float* __restrict__ lg1, float* __restrict__ lg2,
        unsigned short* __restrict__ phiKT, unsigned short* __restrict__ VtT,
        unsigned short* __restrict__ Cws, float* __restrict__ zc) {
    int ch = blockIdx.x;
    int b = ch / NC_, c = ch % NC_;
    int tbase = b * T_ + c * L_;
    int tid = threadIdx.x, lane = tid & 63, w = tid >> 6;
    int l15 = lane & 15, lg4 = lane >> 4;
    size_t cb = (size_t)ch * (D_ * L_);

    __shared__ float s1[L_], s2[L_];
    __shared__ float wL[2][L_];
    __shared__ float sZp[2][256];
    __shared__ unsigned short sKrm[128 * LDK];   // phiK*m  [s][d]
    __shared__ unsigned short sVrm[128 * LDK];   // V       [s][e]

    // ---- cumulative log decays ----
    int t = tid & 127;
    if (tid < 128) {
        float b1b = clampf(1.f / (1.f + __expf(-bb1[0])), 0.01f, 0.995f);
        float b2b = clampf(1.f / (1.f + __expf(-bb2[0])), 0.01f, 0.995f);
        float be = clampf(beta[tbase + t], 0.01f, 0.995f);
        s1[t] = __logf(clampf(b1b * be, 0.01f, 0.995f));
        s2[t] = __logf(clampf(b2b * be, 0.01f, 0.995f));
    }
    __syncthreads();
    for (int off = 1; off < L_; off <<= 1) {
        float a1 = 0.f, a2 = 0.f;
        if (tid < 128 && t >= off) { a1 = s1[t - off]; a2 = s2[t - off]; }
        __syncthreads();
        if (tid < 128) { s1[t] += a1; s2[t] += a2; }
        __syncthreads();
    }
    if (tid < 128) {
        lg1[tbase + t] = s1[t]; lg2[tbase + t] = s2[t];
        float tot1 = s1[L_ - 1], tot2 = s2[L_ - 1];   // hazard-free: full barrier below
    }
    __syncthreads();
    if (tid < 128) {
        wL[0][t] = __expf(s1[L_ - 1] - s1[t]);
        wL[1][t] = __expf(s2[L_ - 1] - s2[t]);
    }

    // ---- stage sKrm (phiK*m) + emit phiKT (A-layout global) ----
#pragma unroll
    for (int p = 0; p < 8; ++p) {
        int i = tid + p * 256;          // 2048 = 128 s x 16 dgrp
        int s = i >> 4, dg = i & 15, d0 = dg * 8;
        const float* kp = &kk[(size_t)(tbase + s) * D_ + d0];
        float4 x0 = *(const float4*)kp;
        float4 x1 = *(const float4*)(kp + 4);
        float m = mask[tbase + s];
        float pq[8] = {phi_f(x0.x)*m, phi_f(x0.y)*m, phi_f(x0.z)*m, phi_f(x0.w)*m,
                       phi_f(x1.x)*m, phi_f(x1.y)*m, phi_f(x1.z)*m, phi_f(x1.w)*m};
        uint4 pk = pack8(pq);
        *(uint4*)&sKrm[s * LDK + d0] = pk;
        *(uint4*)&phiKT[cb + (size_t)((((s >> 4) * 4 + (d0 >> 5)) * 64 + ((d0 >> 3) & 3) * 16 + (s & 15)) * 8)] = pk;
    }
    // ---- stage sVrm ----
#pragma unroll
    for (int p = 0; p < 8; ++p) {
        int i = tid + p * 256;
        int s = i >> 4, eg = i & 15, e0 = eg * 8;
        const float* vp = &vv[(size_t)(tbase + s) * D_ + e0];
        float4 x0 = *(const float4*)vp;
        float4 x1 = *(const float4*)(vp + 4);
        float pv8[8] = {x0.x, x0.y, x0.z, x0.w, x1.x, x1.y, x1.z, x1.w};
        *(uint4*)&sVrm[s * LDK + e0] = pack8(pv8);
    }
    __syncthreads();

    // ---- emit VtT (A-layout of V^T) ----
#pragma unroll
    for (int p = 0; p < 2; ++p) {
        int i = tid + p * 256;          // 512 = 8 mg x 64 lane
        int mg = i >> 6, ln = i & 63;
        int vg4 = ln >> 4, v15 = ln & 15;
#pragma unroll
        for (int ks = 0; ks < 4; ++ks) {
            unsigned short u[8];
#pragma unroll
            for (int j = 0; j < 8; ++j)
                u[j] = sVrm[(ks * 32 + vg4 * 8 + j) * LDK + mg * 16 + v15];
            uint4 r;
            r.x = (unsigned)u[0] | ((unsigned)u[1] << 16);
            r.y = (unsigned)u[2] | ((unsigned)u[3] << 16);
            r.z = (unsigned)u[4] | ((unsigned)u[5] << 16);
            r.w = (unsigned)u[6] | ((unsigned)u[7] << 16);
            *(uint4*)&VtT[cb + (size_t)(((mg * 4 + ks) * 64 + ln) * 8)] = r;
        }
    }

    // ---- zc partials ----
    {
        int zd = tid & 127, zh = tid >> 7;
        float z0 = 0.f, z1 = 0.f;
#pragma unroll
        for (int ss = 0; ss < 64; ++ss) {
            int s = zh * 64 + ss;
            float kv = fbf(sKrm[s * LDK + zd]);
            z0 += wL[0][s] * kv;
            z1 += wL[1][s] * kv;
        }
        sZp[0][tid] = z0; sZp[1][tid] = z1;
    }

    // ---- chunk-state GEMM: Ct[e][d] = sum_s Vt[e][s]*w[st][s]*phiK[s][d] ----
    f32x4 acc[2][2][8];
#pragma unroll
    for (int st = 0; st < 2; ++st)
#pragma unroll
        for (int mm = 0; mm < 2; ++mm)
#pragma unroll
            for (int n = 0; n < 8; ++n) acc[st][mm][n] = zero4();

#pragma unroll
    for (int ks = 0; ks < 4; ++ks) {
        int koff = ks * 32 + lg4 * 8;
        float4 w0a = *(const float4*)&wL[0][koff];
        float4 w0b = *(const float4*)&wL[0][koff + 4];
        float4 w1a = *(const float4*)&wL[1][koff];
        float4 w1b = *(const float4*)&wL[1][koff + 4];
        float wl0[8] = {w0a.x, w0a.y, w0a.z, w0a.w, w0b.x, w0b.y, w0b.z, w0b.w};
        float wl1[8] = {w1a.x, w1a.y, w1a.z, w1a.w, w1b.x, w1b.y, w1b.z, w1b.w};
        bf16x8 as[2][2];
#pragma unroll
        for (int mm = 0; mm < 2; ++mm) {
#pragma unroll
            for (int j = 0; j < 8; ++j) {
                float av = fbf(sVrm[(koff + j) * LDK + (w * 2 + mm) * 16 + l15]);
                as[0][mm][j] = (short)bf16r(av * wl0[j]);
                as[1][mm][j] = (short)bf16r(av * wl1[j]);
            }
        }
#pragma unroll
        for (int n = 0; n < 8; ++n) {
            bf16x8 bb;
#pragma unroll
            for (int j = 0; j < 8; ++j)
                bb[j] = (short)sKrm[(koff + j) * LDK + n * 16 + l15];
#pragma unroll
            for (int st = 0; st < 2; ++st)
#pragma unroll
                for (int mm = 0; mm < 2; ++mm)
                    acc[st][mm][n] = __builtin_amdgcn_mfma_f32_16x16x32_bf16(as[st][mm], bb, acc[st][mm][n], 0, 0, 0);
        }
    }
    __syncthreads();   // sZp ready
    if (tid < 128) {
        zc[((size_t)(0 * B_ + b) * NC_ + c) * D_ + tid] = sZp[0][tid] + sZp[0][tid + 128];
        zc[((size_t)(1 * B_ + b) * NC_ + c) * D_ + tid] = sZp[1][tid] + sZp[1][tid + 128];
    }

    // ---- write Ct tiled (A-layout) ----
#pragma unroll
    for (int st = 0; st < 2; ++st) {
        unsigned short* Cp = Cws + ((size_t)(st * B_ + b) * NC_ + c) * (D_ * D_);
#pragma unroll
        for (int mm = 0; mm < 2; ++mm)
#pragma unroll
            for (int n = 0; n < 8; ++n)
#pragma unroll
                for (int r = 0; r < 4; ++r) {
                    int e = (w * 2 + mm) * 16 + lg4 * 4 + r;
                    int d = n * 16 + l15;
                    Cp[(size_t)((((e >> 4) * 4 + (d >> 5)) * 64 + ((d >> 3) & 3) * 16 + (e & 15)) * 8 + (d & 7))] = bf16r(acc[st][mm][n][r]);
                }
    }
}

// ================= k2f: chunk-state scans (Cws 4/thread + zc), fused =================
__global__ void k2f(unsigned short* __restrict__ Cws, float* __restrict__ zc,
                    const float* __restrict__ lg1, const float* __restrict__ lg2) {
    int g = blockIdx.x * blockDim.x + threadIdx.x;
    if (g < 131072) {            // Cws part: 2*B*D*D/4
        int st = g >> 16;
        int rem = g & 65535;
        int b = rem >> 12;
        int de = (rem & 4095) * 4;
        const float* lg = st ? lg2 : lg1;
        size_t base = ((size_t)(st * B_ + b) * NC_) * (D_ * D_) + de;
        float run0 = 0.f, run1 = 0.f, run2 = 0.f, run3 = 0.f;
        for (int c = 0; c < NC_; c++) {
            float a = __expf(lg[b * T_ + c * L_ + L_ - 1]);
            uint2 val = *(uint2*)&Cws[base + (size_t)c * (D_ * D_)];
            float t0 = fbf((unsigned short)(val.x & 0xffff)), t1 = fbf((unsigned short)(val.x >> 16));
            float t2 = fbf((unsigned short)(val.y & 0xffff)), t3 = fbf((unsigned short)(val.y >> 16));
            uint2 wv; wv.x = pack2bf(run0, run1); wv.y = pack2bf(run2, run3);
            *(uint2*)&Cws[base + (size_t)c * (D_ * D_)] = wv;
            run0 = a * run0 + t0; run1 = a * run1 + t1;
            run2 = a * run2 + t2; run3 = a * run3 + t3;
        }
    } else {                     // zc part: 2*B*D threads
        int gz = g - 131072;
        int st = gz >> 11;
        int rem = gz & 2047;
        int b = rem >> 7;
        int d = rem & 127;
        const float* lg = st ? lg2 : lg1;
        size_t base = ((size_t)(st * B_ + b) * NC_) * D_ + d;
        float run = 0.f;
        for (int c = 0; c < NC_; c++) {
            float a = __expf(lg[b * T_ + c * L_ + L_ - 1]);
            float tmp = zc[base + (size_t)c * D_];
            zc[base + (size_t)c * D_] = run;
            run = a * run + tmp;
        }
    }
}

// ================= k3: one block per chunk, 2 t-tiles/wave, deep batching =================
__global__ __launch_bounds__(256, 2) void k3_v6(
        const float* __restrict__ qq, const float* __restrict__ mask,
        const float* __restrict__ lg1, const float* __restrict__ lg2,
        const unsigned short* __restrict__ phiKT, const unsigned short* __restrict__ VtT,
        const unsigned short* __restrict__ Cws, const float* __restrict__ zc,
        float* __restrict__ out) {
    __shared__ unsigned short bufP[4][32 * LDP];   // per-wave P^T (32 t-rows x 128 s)
    int ch = blockIdx.x;
    int b = ch / NC_, c = ch % NC_;
    int tbase = b * T_ + c * L_;
    int tid = threadIdx.x, lane = tid & 63, w = tid >> 6;
    int l15 = lane & 15, lg4 = lane >> 4;
    unsigned short* bufPw = &bufP[w][0];
    size_t cb = (size_t)ch * 16384;

    int trow0 = w * 16 + l15, trow1 = 64 + trow0;
    size_t gt0 = (size_t)(tbase + trow0), gt1 = (size_t)(tbase + trow1);

    float lg1t0 = lg1[gt0], lg2t0 = lg2[gt0], mt0 = mask[gt0];
    float lg1t1 = lg1[gt1], lg2t1 = lg2[gt1], mt1 = mask[gt1];
    float a1t0 = __expf(lg1t0), a2t0 = __expf(lg2t0);
    float a1t1 = __expf(lg1t1), a2t1 = __expf(lg2t1);

    // ---- phiQ B-fragments (both t-tiles) ----
    bf16x8 qf0[4], qf1[4];
#pragma unroll
    for (int ks = 0; ks < 4; ++ks) {
        int koff = ks * 32 + lg4 * 8;
        const float* qp0 = &qq[gt0 * D_ + koff];
        const float* qp1 = &qq[gt1 * D_ + koff];
        float4 x0 = *(const float4*)qp0, x1 = *(const float4*)(qp0 + 4);
        float4 y0 = *(const float4*)qp1, y1 = *(const float4*)(qp1 + 4);
        float p0[8] = {phi_f(x0.x), phi_f(x0.y), phi_f(x0.z), phi_f(x0.w),
                       phi_f(x1.x), phi_f(x1.y), phi_f(x1.z), phi_f(x1.w)};
        float p1[8] = {phi_f(y0.x), phi_f(y0.y), phi_f(y0.z), phi_f(y0.w),
                       phi_f(y1.x), phi_f(y1.y), phi_f(y1.z), phi_f(y1.w)};
#pragma unroll
        for (int j = 0; j < 8; ++j) {
            qf0[ks][j] = (short)bf16r(p0[j]);
            qf1[ks][j] = (short)bf16r(p1[j]);
        }
    }

    // ---- den inter-chunk dots ----
    const float* z1p = &zc[((size_t)(0 * B_ + b) * NC_ + c) * D_];
    const float* z2p = &zc[((size_t)(1 * B_ + b) * NC_ + c) * D_];
    float d1_0 = 0.f, d2_0 = 0.f, d1_1 = 0.f, d2_1 = 0.f;
#pragma unroll
    for (int ks = 0; ks < 4; ++ks) {
        int off = ks * 32 + lg4 * 8;
        float4 za = *(const float4*)(z1p + off), zb = *(const float4*)(z1p + off + 4);
        float4 zca = *(const float4*)(z2p + off), zcb = *(const float4*)(z2p + off + 4);
        float z1a[8] = {za.x, za.y, za.z, za.w, zb.x, zb.y, zb.z, zb.w};
        float z2a[8] = {zca.x, zca.y, zca.z, zca.w, zcb.x, zcb.y, zcb.z, zcb.w};
#pragma unroll
        for (int j = 0; j < 8; ++j) {
            float fq0 = fbf((unsigned short)qf0[ks][j]);
            float fq1 = fbf((unsigned short)qf1[ks][j]);
            d1_0 += fq0 * z1a[j]; d2_0 += fq0 * z2a[j];
            d1_1 += fq1 * z1a[j]; d2_1 += fq1 * z2a[j];
        }
    }
    d1_0 += __shfl_xor(d1_0, 16); d1_0 += __shfl_xor(d1_0, 32);
    d2_0 += __shfl_xor(d2_0, 16); d2_0 += __shfl_xor(d2_0, 32);
    d1_1 += __shfl_xor(d1_1, 16); d1_1 += __shfl_xor(d1_1, 32);
    d2_1 += __shfl_xor(d2_1, 16); d2_1 += __shfl_xor(d2_1, 32);

    // ---- S^T + P (per mh group of 4 s-tiles); kf batched 16-deep ----
    float rs0 = 0.f, rs1 = 0.f;
#pragma unroll
    for (int mh = 0; mh < 2; ++mh) {
        bf16x8 kf[16];
#pragma unroll
        for (int mm = 0; mm < 4; ++mm)
#pragma unroll
            for (int ks = 0; ks < 4; ++ks)
                kf[mm * 4 + ks] = *(const bf16x8*)&phiKT[cb + (size_t)(((((mh * 4 + mm) * 4) + ks) * 64 + lane) * 8)];
        f32x4 acc0[4], acc1[4];
#pragma unroll
        for (int mm = 0; mm < 4; ++mm) { acc0[mm] = zero4(); acc1[mm] = zero4(); }
#pragma unroll
        for (int ks = 0; ks < 4; ++ks)
#pragma unroll
            for (int mm = 0; mm < 4; ++mm) {
                if (mh == 0)
                    acc0[mm] = __builtin_amdgcn_mfma_f32_16x16x32_bf16(kf[mm * 4 + ks], qf0[ks], acc0[mm], 0, 0, 0);
                acc1[mm] = __builtin_amdgcn_mfma_f32_16x16x32_bf16(kf[mm * 4 + ks], qf1[ks], acc1[mm], 0, 0, 0);
            }
        // decay/mask -> P^T into bufP
#pragma unroll
        for (int mm = 0; mm < 4; ++mm) {
            int s0 = (mh * 4 + mm) * 16 + lg4 * 4;
            float4 l1s = *(const float4*)&lg1[tbase + s0];
            float4 l2s = *(const float4*)&lg2[tbase + s0];
            float l1a[4] = {l1s.x, l1s.y, l1s.z, l1s.w};
            float l2a[4] = {l2s.x, l2s.y, l2s.z, l2s.w};
            if (mh == 0) {
                float pv[4];
#pragma unroll
                for (int r = 0; r < 4; ++r) {
                    int s = s0 + r;
                    float p = 0.f;
                    if (s <= trow0)
                        p = acc0[mm][r] * (__expf(lg1t0 - l1a[r]) + __expf(lg2t0 - l2a[r]));
                    pv[r] = p; rs0 += p;
                }
                uint2 dd; dd.x = pack2bf(pv[0], pv[1]); dd.y = pack2bf(pv[2], pv[3]);
                *(uint2*)&bufPw[l15 * LDP + s0] = dd;
            }
            {
                float pv[4];
#pragma unroll
                for (int r = 0; r < 4; ++r) {
                    int s = s0 + r;
                    float p = 0.f;
                    if (s <= trow1)
                        p = acc1[mm][r] * (__expf(lg1t1 - l1a[r]) + __expf(lg2t1 - l2a[r]));
                    pv[r] = p; rs1 += p;
                }
                uint2 dd; dd.x = pack2bf(pv[0], pv[1]); dd.y = pack2bf(pv[2], pv[3]);
                *(uint2*)&bufPw[(16 + l15) * LDP + s0] = dd;
            }
        }
    }
    rs0 += __shfl_xor(rs0, 16); rs0 += __shfl_xor(rs0, 32);
    rs1 += __shfl_xor(rs1, 16); rs1 += __shfl_xor(rs1, 32);
    float osc0 = mt0 / fmaxf(a1t0 * d1_0 + a2t0 * d2_0 + rs0, 1e-6f);
    float osc1 = mt1 / fmaxf(a1t1 * d1_1 + a2t1 * d2_1 + rs1, 1e-6f);

    // ---- QH: acc += (a_st*phiQ) . H_st, hf batched 16-deep ----
    f32x4 acc_o0[8], acc_o1[8];
#pragma unroll
    for (int m = 0; m < 8; ++m) { acc_o0[m] = zero4(); acc_o1[m] = zero4(); }
#pragma unroll
    for (int st = 0; st < 2; ++st) {
        const unsigned short* Hp = Cws + ((size_t)(st * B_ + b) * NC_ + c) * (D_ * D_);
        float sc0 = st ? a2t0 : a1t0;
        float sc1 = st ? a2t1 : a1t1;
#pragma unroll
        for (int ks2 = 0; ks2 < 2; ++ks2) {
            bf16x8 hf[16];
#pragma unroll
            for (int kq = 0; kq < 2; ++kq)
#pragma unroll
                for (int m = 0; m < 8; ++m)
                    hf[kq * 8 + m] = *(const bf16x8*)&Hp[(size_t)(((m * 4 + ks2 * 2 + kq) * 64 + lane) * 8)];
#pragma unroll
            for (int kq = 0; kq < 2; ++kq) {
                int ks = ks2 * 2 + kq;
                bf16x8 qs0, qs1;
#pragma unroll
                for (int j = 0; j < 8; ++j) {
                    qs0[j] = (short)bf16r(fbf((unsigned short)qf0[ks][j]) * sc0);
                    qs1[j] = (short)bf16r(fbf((unsigned short)qf1[ks][j]) * sc1);
                }
#pragma unroll
                for (int m = 0; m < 8; ++m) {
                    acc_o0[m] = __builtin_amdgcn_mfma_f32_16x16x32_bf16(hf[kq * 8 + m], qs0, acc_o0[m], 0, 0, 0);
                    acc_o1[m] = __builtin_amdgcn_mfma_f32_16x16x32_bf16(hf[kq * 8 + m], qs1, acc_o1[m], 0, 0, 0);
                }
            }
        }
    }

    // ---- PV: acc += Vt @ P^T, vf batched 8-deep ----
#pragma unroll
    for (int ks = 0; ks < 4; ++ks) {
        bf16x8 vf[8];
#pragma unroll
        for (int m = 0; m < 8; ++m)
            vf[m] = *(const bf16x8*)&VtT[cb + (size_t)(((m * 4 + ks) * 64 + lane) * 8)];
        bf16x8 pf1 = *(const bf16x8*)&bufPw[(16 + l15) * LDP + ks * 32 + lg4 * 8];
        if (ks < 2) {
            bf16x8 pf0 = *(const bf16x8*)&bufPw[l15 * LDP + ks * 32 + lg4 * 8];
#pragma unroll
            for (int m = 0; m < 8; ++m)
                acc_o0[m] = __builtin_amdgcn_mfma_f32_16x16x32_bf16(vf[m], pf0, acc_o0[m], 0, 0, 0);
        }
#pragma unroll
        for (int m = 0; m < 8; ++m)
            acc_o1[m] = __builtin_amdgcn_mfma_f32_16x16x32_bf16(vf[m], pf1, acc_o1[m], 0, 0, 0);
    }

    // ---- store ----
#pragma unroll
    for (int m = 0; m < 8; ++m) {
        float4 o0, o1;
        o0.x = acc_o0[m][0] * osc0; o0.y = acc_o0[m][1] * osc0;
        o0.z = acc_o0[m][2] * osc0; o0.w = acc_o0[m][3] * osc0;
        o1.x = acc_o1[m][0] * osc1; o1.y = acc_o1[m][1] * osc1;
        o1.z = acc_o1[m][2] * osc1; o1.w = acc_o1[m][3] * osc1;
        *(float4*)&out[gt0 * D_ + m * 16 + lg4 * 4] = o0;
        *(float4*)&out[gt1 * D_ + m * 16 + lg4 * 4] = o1;
    }
}

extern "C" void kernel_launch(void* const* d_in, const int* in_sizes, int n_in,
                              void* d_out, int out_size, void* d_ws, size_t ws_size,
                              hipStream_t stream) {
    const float* q    = (const float*)d_in[0];
    const float* k    = (const float*)d_in[1];
    const float* v    = (const float*)d_in[2];
    const float* beta = (const float*)d_in[3];
    const float* mask = (const float*)d_in[4];
    const float* bb1  = (const float*)d_in[5];
    const float* bb2  = (const float*)d_in[6];
    float* out = (float*)d_out;

    size_t n_lg = (size_t)B_ * T_;                       // 65536
    size_t n_z  = (size_t)2 * B_ * NC_ * D_;             // 131072
    size_t n_C  = (size_t)2 * B_ * NC_ * D_ * D_;        // 16777216 bf16
    size_t n_kt = (size_t)B_ * T_ * D_;                  // 8388608 bf16
    size_t need = (2 * n_lg + n_z) * sizeof(float) + (n_C + 2 * n_kt) * sizeof(unsigned short);
    if (ws_size < need) return;

    float* lg1 = (float*)d_ws;
    float* lg2 = lg1 + n_lg;
    float* zc  = lg2 + n_lg;
    unsigned short* Cws   = (unsigned short*)(zc + n_z);
    unsigned short* phiKT = Cws + n_C;
    unsigned short* VtT   = phiKT + n_kt;

    kA<<<CH_, 256, 0, stream>>>(beta, bb1, bb2, k, v, mask, lg1, lg2, phiKT, VtT, Cws, zc);
    k2f<<<528, 256, 0, stream>>>(Cws, zc, lg1, lg2);
    k3_v6<<<CH_, 256, 0, stream>>>(q, mask, lg1, lg2, phiKT, VtT, Cws, zc, out);
}

// Round 7
// 78.378 us; speedup vs baseline: 2.6383x; 1.0857x over previous
//
#include <hip/hip_runtime.h>

#define B_ 16
#define T_ 4096
#define D_ 128
#define L_ 128
#define NC_ 32            // T_/L_
#define CH_ (B_*NC_)      // 512 chunks
#define LDK 136           // padded bf16 row stride (272B)
#define LDP 136
// XOR-swizzle of the s-column (bits 3..5) by row: spreads transpose writes and
// keeps 8-element s-blocks contiguous for ds_read_b128.
#define XS(row, scol) ((scol) ^ ((((row) >> 3) & 7) << 3))

typedef __attribute__((ext_vector_type(8))) short bf16x8;
typedef __attribute__((ext_vector_type(4))) float f32x4;

__device__ __forceinline__ float clampf(float x, float lo, float hi) {
    return fminf(fmaxf(x, lo), hi);
}
__device__ __forceinline__ float phi_f(float x) {   // elu(x)+1
    return x > 0.f ? x + 1.f : __expf(x);
}
__device__ __forceinline__ unsigned short bf16r(float f) {  // RNE f32->bf16
    unsigned u = __builtin_bit_cast(unsigned, f);
    u += 0x7FFFu + ((u >> 16) & 1u);
    return (unsigned short)(u >> 16);
}
__device__ __forceinline__ float fbf(unsigned short h) {
    unsigned u = ((unsigned)h) << 16; return __builtin_bit_cast(float, u);
}
__device__ __forceinline__ unsigned pack2bf(float a, float b) {
    return (unsigned)bf16r(a) | ((unsigned)bf16r(b) << 16);
}
__device__ __forceinline__ uint4 pack8(const float* f) {
    uint4 r;
    r.x = pack2bf(f[0], f[1]); r.y = pack2bf(f[2], f[3]);
    r.z = pack2bf(f[4], f[5]); r.w = pack2bf(f[6], f[7]);
    return r;
}
__device__ __forceinline__ f32x4 zero4() { f32x4 z; z[0]=0.f; z[1]=0.f; z[2]=0.f; z[3]=0.f; return z; }

// Fragment-tiled (A-layout) index for a 128(row) x 128(k) bf16 matrix:
//   flat = ((rowtile*4 + ktile)*64 + (kgrp*16 + row15))*8 + j
//   element [row = rowtile*16 + row15][k = ktile*32 + kgrp*8 + j]

// ================= kA v3: cumlog + swizzled-LDS staging + vector GEMM =================
__global__ __launch_bounds__(256, 2) void kA(
        const float* __restrict__ beta,
        const float* __restrict__ bb1, const float* __restrict__ bb2,
        const float* __restrict__ kk, const float* __restrict__ vv,
        const float* __restrict__ mask,
        float* __restrict__ lg1, float* __restrict__ lg2,
        unsigned short* __restrict__ phiKT, unsigned short* __restrict__ VtT,
        unsigned short* __restrict__ Cws, float* __restrict__ zc) {
    int ch = blockIdx.x;
    int b = ch / NC_, c = ch % NC_;
    int tbase = b * T_ + c * L_;
    int tid = threadIdx.x, lane = tid & 63, w = tid >> 6;
    int l15 = lane & 15, lg4 = lane >> 4;
    size_t cb = (size_t)ch * (D_ * L_);

    __shared__ float sL1[L_], sL2[L_];
    __shared__ float wL[2][L_];
    __shared__ float wtot[2][2];
    __shared__ unsigned short sKt[128 * LDK];   // phiK*m ^T [d][s], s swizzled
    __shared__ unsigned short sVt[128 * LDK];   // V^T [e][s], s swizzled

    // ---- cumlog scan: 2 waves, shfl_up, 1 barrier ----
    if (w < 2) {
        int t = w * 64 + lane;
        float b1b = clampf(1.f / (1.f + __expf(-bb1[0])), 0.01f, 0.995f);
        float b2b = clampf(1.f / (1.f + __expf(-bb2[0])), 0.01f, 0.995f);
        float be = clampf(beta[tbase + t], 0.01f, 0.995f);
        float x1 = __logf(clampf(b1b * be, 0.01f, 0.995f));
        float x2 = __logf(clampf(b2b * be, 0.01f, 0.995f));
#pragma unroll
        for (int off = 1; off < 64; off <<= 1) {
            float y1 = __shfl_up(x1, off);
            float y2 = __shfl_up(x2, off);
            if (lane >= off) { x1 += y1; x2 += y2; }
        }
        if (lane == 63) { wtot[0][w] = x1; wtot[1][w] = x2; }
        sL1[t] = x1; sL2[t] = x2;
    }
    __syncthreads();
    if (tid < 128) {
        int t = tid;
        float x1 = sL1[t], x2 = sL2[t];
        if (t >= 64) { x1 += wtot[0][0]; x2 += wtot[1][0]; }
        float tot1 = wtot[0][0] + wtot[0][1];
        float tot2 = wtot[1][0] + wtot[1][1];
        lg1[tbase + t] = x1; lg2[tbase + t] = x2;
        wL[0][t] = __expf(tot1 - x1);
        wL[1][t] = __expf(tot2 - x2);
    }

    // ---- stage K: (s, 8d) -> phiKT global (coalesced) + sKt transposed (swizzled) ----
#pragma unroll
    for (int p = 0; p < 8; ++p) {
        int i = tid + p * 256;          // 2048 = 128 s x 16 dgrp
        int s = i >> 4, dg = i & 15, d0 = dg * 8;
        const float* kp = &kk[(size_t)(tbase + s) * D_ + d0];
        float4 x0 = *(const float4*)kp, x1 = *(const float4*)(kp + 4);
        float m = mask[tbase + s];
        float pq[8] = {phi_f(x0.x)*m, phi_f(x0.y)*m, phi_f(x0.z)*m, phi_f(x0.w)*m,
                       phi_f(x1.x)*m, phi_f(x1.y)*m, phi_f(x1.z)*m, phi_f(x1.w)*m};
        uint4 pk = pack8(pq);
        *(uint4*)&phiKT[cb + (size_t)((((s >> 4) * 4 + (d0 >> 5)) * 64 + ((d0 >> 3) & 3) * 16 + (s & 15)) * 8)] = pk;
        unsigned short pu[8] = {
            (unsigned short)(pk.x & 0xffff), (unsigned short)(pk.x >> 16),
            (unsigned short)(pk.y & 0xffff), (unsigned short)(pk.y >> 16),
            (unsigned short)(pk.z & 0xffff), (unsigned short)(pk.z >> 16),
            (unsigned short)(pk.w & 0xffff), (unsigned short)(pk.w >> 16)};
#pragma unroll
        for (int j = 0; j < 8; ++j) {
            int row = d0 + j;
            sKt[row * LDK + XS(row, s)] = pu[j];
        }
    }
    // ---- stage V transposed (swizzled) ----
#pragma unroll
    for (int p = 0; p < 8; ++p) {
        int i = tid + p * 256;
        int s = i >> 4, eg = i & 15, e0 = eg * 8;
        const float* vp = &vv[(size_t)(tbase + s) * D_ + e0];
        float4 x0 = *(const float4*)vp, x1 = *(const float4*)(vp + 4);
        float pv8[8] = {x0.x, x0.y, x0.z, x0.w, x1.x, x1.y, x1.z, x1.w};
        uint4 pk = pack8(pv8);
        unsigned short pu[8] = {
            (unsigned short)(pk.x & 0xffff), (unsigned short)(pk.x >> 16),
            (unsigned short)(pk.y & 0xffff), (unsigned short)(pk.y >> 16),
            (unsigned short)(pk.z & 0xffff), (unsigned short)(pk.z >> 16),
            (unsigned short)(pk.w & 0xffff), (unsigned short)(pk.w >> 16)};
#pragma unroll
        for (int j = 0; j < 8; ++j) {
            int row = e0 + j;
            sVt[row * LDK + XS(row, s)] = pu[j];
        }
    }
    __syncthreads();

    // ---- VtT emit: vector reads from sVt, coalesced uint4 global stores ----
#pragma unroll
    for (int p = 0; p < 2; ++p) {
        int i = tid + p * 256;          // 512 = 8 mg x 64 ln
        int mg = i >> 6, ln = i & 63;
        int row = mg * 16 + (ln & 15);
#pragma unroll
        for (int ks = 0; ks < 4; ++ks) {
            int col = ks * 32 + (ln >> 4) * 8;
            uint4 r = *(const uint4*)&sVt[row * LDK + XS(row, col)];
            *(uint4*)&VtT[cb + (size_t)(((mg * 4 + ks) * 64 + ln) * 8)] = r;
        }
    }

    // ---- zc: vectorized row dot  zc[st][d] = sum_s wL[st][s]*phiKm[s][d] ----
    {
        int st = tid >> 7, d = tid & 127;
        float acc = 0.f;
#pragma unroll
        for (int s8 = 0; s8 < 16; ++s8) {
            uint4 kv = *(const uint4*)&sKt[d * LDK + XS(d, s8 * 8)];
            const float* wp = &wL[st][s8 * 8];
            acc += fbf((unsigned short)(kv.x & 0xffff)) * wp[0] + fbf((unsigned short)(kv.x >> 16)) * wp[1]
                 + fbf((unsigned short)(kv.y & 0xffff)) * wp[2] + fbf((unsigned short)(kv.y >> 16)) * wp[3]
                 + fbf((unsigned short)(kv.z & 0xffff)) * wp[4] + fbf((unsigned short)(kv.z >> 16)) * wp[5]
                 + fbf((unsigned short)(kv.w & 0xffff)) * wp[6] + fbf((unsigned short)(kv.w >> 16)) * wp[7];
        }
        zc[((size_t)(st * B_ + b) * NC_ + c) * D_ + d] = acc;
    }

    // ---- GEMM: Ct[e][d] = sum_s (V[s][e]*w[st][s]) * phiKm[s][d], vector LDS reads ----
    f32x4 acc[2][2][8];
#pragma unroll
    for (int st = 0; st < 2; ++st)
#pragma unroll
        for (int mm = 0; mm < 2; ++mm)
#pragma unroll
            for (int n = 0; n < 8; ++n) acc[st][mm][n] = zero4();

#pragma unroll
    for (int ks = 0; ks < 4; ++ks) {
        int koff = ks * 32 + lg4 * 8;
        float wl0[8], wl1[8];
        {
            float4 a0 = *(const float4*)&wL[0][koff];
            float4 a1 = *(const float4*)&wL[0][koff + 4];
            float4 b0 = *(const float4*)&wL[1][koff];
            float4 b1 = *(const float4*)&wL[1][koff + 4];
            wl0[0]=a0.x; wl0[1]=a0.y; wl0[2]=a0.z; wl0[3]=a0.w;
            wl0[4]=a1.x; wl0[5]=a1.y; wl0[6]=a1.z; wl0[7]=a1.w;
            wl1[0]=b0.x; wl1[1]=b0.y; wl1[2]=b0.z; wl1[3]=b0.w;
            wl1[4]=b1.x; wl1[5]=b1.y; wl1[6]=b1.z; wl1[7]=b1.w;
        }
        bf16x8 as0[2], as1[2];
#pragma unroll
        for (int mm = 0; mm < 2; ++mm) {
            int row = (w * 2 + mm) * 16 + l15;
            bf16x8 vt = *(const bf16x8*)&sVt[row * LDK + XS(row, koff)];
#pragma unroll
            for (int j = 0; j < 8; ++j) {
                float av = fbf((unsigned short)vt[j]);
                as0[mm][j] = (short)bf16r(av * wl0[j]);
                as1[mm][j] = (short)bf16r(av * wl1[j]);
            }
        }
#pragma unroll
        for (int n = 0; n < 8; ++n) {
            int row = n * 16 + l15;
            bf16x8 bb = *(const bf16x8*)&sKt[row * LDK + XS(row, koff)];
            acc[0][0][n] = __builtin_amdgcn_mfma_f32_16x16x32_bf16(as0[0], bb, acc[0][0][n], 0, 0, 0);
            acc[0][1][n] = __builtin_amdgcn_mfma_f32_16x16x32_bf16(as0[1], bb, acc[0][1][n], 0, 0, 0);
            acc[1][0][n] = __builtin_amdgcn_mfma_f32_16x16x32_bf16(as1[0], bb, acc[1][0][n], 0, 0, 0);
            acc[1][1][n] = __builtin_amdgcn_mfma_f32_16x16x32_bf16(as1[1], bb, acc[1][1][n], 0, 0, 0);
        }
    }
    __syncthreads();   // all sKt/sVt reads done

    // ---- Ct writeback: scalar LDS scatter (A-layout), then coalesced global emit ----
#pragma unroll
    for (int st = 0; st < 2; ++st) {
        unsigned short* basep = st ? sVt : sKt;
#pragma unroll
        for (int mm = 0; mm < 2; ++mm)
#pragma unroll
            for (int n = 0; n < 8; ++n)
#pragma unroll
                for (int r = 0; r < 4; ++r) {
                    int e = (w * 2 + mm) * 16 + lg4 * 4 + r;
                    int d = n * 16 + l15;
                    basep[(((e >> 4) * 4 + (d >> 5)) * 64 + ((d >> 3) & 3) * 16 + (e & 15)) * 8 + (d & 7)] = bf16r(acc[st][mm][n][r]);
                }
    }
    __syncthreads();
#pragma unroll
    for (int st = 0; st < 2; ++st) {
        const unsigned short* basep = st ? sVt : sKt;
        unsigned short* Cp = Cws + ((size_t)(st * B_ + b) * NC_ + c) * (D_ * D_);
#pragma unroll
        for (int p = 0; p < 8; ++p) {
            int i = tid + p * 256;   // 2048 octets
            *(uint4*)&Cp[(size_t)i * 8] = *(const uint4*)&basep[i * 8];
        }
    }
}

// ================= k2f: chunk-state scans (Cws 4/thread + zc), fused =================
__global__ void k2f(unsigned short* __restrict__ Cws, float* __restrict__ zc,
                    const float* __restrict__ lg1, const float* __restrict__ lg2) {
    int g = blockIdx.x * blockDim.x + threadIdx.x;
    if (g < 131072) {            // Cws part: 2*B*D*D/4
        int st = g >> 16;
        int rem = g & 65535;
        int b = rem >> 12;
        int de = (rem & 4095) * 4;
        const float* lg = st ? lg2 : lg1;
        size_t base = ((size_t)(st * B_ + b) * NC_) * (D_ * D_) + de;
        float run0 = 0.f, run1 = 0.f, run2 = 0.f, run3 = 0.f;
        for (int c = 0; c < NC_; c++) {
            float a = __expf(lg[b * T_ + c * L_ + L_ - 1]);
            uint2 val = *(uint2*)&Cws[base + (size_t)c * (D_ * D_)];
            float t0 = fbf((unsigned short)(val.x & 0xffff)), t1 = fbf((unsigned short)(val.x >> 16));
            float t2 = fbf((unsigned short)(val.y & 0xffff)), t3 = fbf((unsigned short)(val.y >> 16));
            uint2 wv; wv.x = pack2bf(run0, run1); wv.y = pack2bf(run2, run3);
            *(uint2*)&Cws[base + (size_t)c * (D_ * D_)] = wv;
            run0 = a * run0 + t0; run1 = a * run1 + t1;
            run2 = a * run2 + t2; run3 = a * run3 + t3;
        }
    } else {                     // zc part: 2*B*D threads
        int gz = g - 131072;
        int st = gz >> 11;
        int rem = gz & 2047;
        int b = rem >> 7;
        int d = rem & 127;
        const float* lg = st ? lg2 : lg1;
        size_t base = ((size_t)(st * B_ + b) * NC_) * D_ + d;
        float run = 0.f;
        for (int c = 0; c < NC_; c++) {
            float a = __expf(lg[b * T_ + c * L_ + L_ - 1]);
            float tmp = zc[base + (size_t)c * D_];
            zc[base + (size_t)c * D_] = run;
            run = a * run + tmp;
        }
    }
}

// ================= k3: one block per chunk, 2 t-tiles/wave, deep batching =================
__global__ __launch_bounds__(256, 2) void k3_v6(
        const float* __restrict__ qq, const float* __restrict__ mask,
        const float* __restrict__ lg1, const float* __restrict__ lg2,
        const unsigned short* __restrict__ phiKT, const unsigned short* __restrict__ VtT,
        const unsigned short* __restrict__ Cws, const float* __restrict__ zc,
        float* __restrict__ out) {
    __shared__ unsigned short bufP[4][32 * LDP];   // per-wave P^T (32 t-rows x 128 s)
    int ch = blockIdx.x;
    int b = ch / NC_, c = ch % NC_;
    int tbase = b * T_ + c * L_;
    int tid = threadIdx.x, lane = tid & 63, w = tid >> 6;
    int l15 = lane & 15, lg4 = lane >> 4;
    unsigned short* bufPw = &bufP[w][0];
    size_t cb = (size_t)ch * 16384;

    int trow0 = w * 16 + l15, trow1 = 64 + trow0;
    size_t gt0 = (size_t)(tbase + trow0), gt1 = (size_t)(tbase + trow1);

    float lg1t0 = lg1[gt0], lg2t0 = lg2[gt0], mt0 = mask[gt0];
    float lg1t1 = lg1[gt1], lg2t1 = lg2[gt1], mt1 = mask[gt1];
    float a1t0 = __expf(lg1t0), a2t0 = __expf(lg2t0);
    float a1t1 = __expf(lg1t1), a2t1 = __expf(lg2t1);

    // ---- phiQ B-fragments (both t-tiles) ----
    bf16x8 qf0[4], qf1[4];
#pragma unroll
    for (int ks = 0; ks < 4; ++ks) {
        int koff = ks * 32 + lg4 * 8;
        const float* qp0 = &qq[gt0 * D_ + koff];
        const float* qp1 = &qq[gt1 * D_ + koff];
        float4 x0 = *(const float4*)qp0, x1 = *(const float4*)(qp0 + 4);
        float4 y0 = *(const float4*)qp1, y1 = *(const float4*)(qp1 + 4);
        float p0[8] = {phi_f(x0.x), phi_f(x0.y), phi_f(x0.z), phi_f(x0.w),
                       phi_f(x1.x), phi_f(x1.y), phi_f(x1.z), phi_f(x1.w)};
        float p1[8] = {phi_f(y0.x), phi_f(y0.y), phi_f(y0.z), phi_f(y0.w),
                       phi_f(y1.x), phi_f(y1.y), phi_f(y1.z), phi_f(y1.w)};
#pragma unroll
        for (int j = 0; j < 8; ++j) {
            qf0[ks][j] = (short)bf16r(p0[j]);
            qf1[ks][j] = (short)bf16r(p1[j]);
        }
    }

    // ---- den inter-chunk dots ----
    const float* z1p = &zc[((size_t)(0 * B_ + b) * NC_ + c) * D_];
    const float* z2p = &zc[((size_t)(1 * B_ + b) * NC_ + c) * D_];
    float d1_0 = 0.f, d2_0 = 0.f, d1_1 = 0.f, d2_1 = 0.f;
#pragma unroll
    for (int ks = 0; ks < 4; ++ks) {
        int off = ks * 32 + lg4 * 8;
        float4 za = *(const float4*)(z1p + off), zb = *(const float4*)(z1p + off + 4);
        float4 zca = *(const float4*)(z2p + off), zcb = *(const float4*)(z2p + off + 4);
        float z1a[8] = {za.x, za.y, za.z, za.w, zb.x, zb.y, zb.z, zb.w};
        float z2a[8] = {zca.x, zca.y, zca.z, zca.w, zcb.x, zcb.y, zcb.z, zcb.w};
#pragma unroll
        for (int j = 0; j < 8; ++j) {
            float fq0 = fbf((unsigned short)qf0[ks][j]);
            float fq1 = fbf((unsigned short)qf1[ks][j]);
            d1_0 += fq0 * z1a[j]; d2_0 += fq0 * z2a[j];
            d1_1 += fq1 * z1a[j]; d2_1 += fq1 * z2a[j];
        }
    }
    d1_0 += __shfl_xor(d1_0, 16); d1_0 += __shfl_xor(d1_0, 32);
    d2_0 += __shfl_xor(d2_0, 16); d2_0 += __shfl_xor(d2_0, 32);
    d1_1 += __shfl_xor(d1_1, 16); d1_1 += __shfl_xor(d1_1, 32);
    d2_1 += __shfl_xor(d2_1, 16); d2_1 += __shfl_xor(d2_1, 32);

    // ---- S^T + P (per mh group of 4 s-tiles); kf batched 16-deep ----
    float rs0 = 0.f, rs1 = 0.f;
#pragma unroll
    for (int mh = 0; mh < 2; ++mh) {
        bf16x8 kf[16];
#pragma unroll
        for (int mm = 0; mm < 4; ++mm)
#pragma unroll
            for (int ks = 0; ks < 4; ++ks)
                kf[mm * 4 + ks] = *(const bf16x8*)&phiKT[cb + (size_t)(((((mh * 4 + mm) * 4) + ks) * 64 + lane) * 8)];
        f32x4 acc0[4], acc1[4];
#pragma unroll
        for (int mm = 0; mm < 4; ++mm) { acc0[mm] = zero4(); acc1[mm] = zero4(); }
#pragma unroll
        for (int ks = 0; ks < 4; ++ks)
#pragma unroll
            for (int mm = 0; mm < 4; ++mm) {
                if (mh == 0)
                    acc0[mm] = __builtin_amdgcn_mfma_f32_16x16x32_bf16(kf[mm * 4 + ks], qf0[ks], acc0[mm], 0, 0, 0);
                acc1[mm] = __builtin_amdgcn_mfma_f32_16x16x32_bf16(kf[mm * 4 + ks], qf1[ks], acc1[mm], 0, 0, 0);
            }
        // decay/mask -> P^T into bufP
#pragma unroll
        for (int mm = 0; mm < 4; ++mm) {
            int s0 = (mh * 4 + mm) * 16 + lg4 * 4;
            float4 l1s = *(const float4*)&lg1[tbase + s0];
            float4 l2s = *(const float4*)&lg2[tbase + s0];
            float l1a[4] = {l1s.x, l1s.y, l1s.z, l1s.w};
            float l2a[4] = {l2s.x, l2s.y, l2s.z, l2s.w};
            if (mh == 0) {
                float pv[4];
#pragma unroll
                for (int r = 0; r < 4; ++r) {
                    int s = s0 + r;
                    float p = 0.f;
                    if (s <= trow0)
                        p = acc0[mm][r] * (__expf(lg1t0 - l1a[r]) + __expf(lg2t0 - l2a[r]));
                    pv[r] = p; rs0 += p;
                }
                uint2 dd; dd.x = pack2bf(pv[0], pv[1]); dd.y = pack2bf(pv[2], pv[3]);
                *(uint2*)&bufPw[l15 * LDP + s0] = dd;
            }
            {
                float pv[4];
#pragma unroll
                for (int r = 0; r < 4; ++r) {
                    int s = s0 + r;
                    float p = 0.f;
                    if (s <= trow1)
                        p = acc1[mm][r] * (__expf(lg1t1 - l1a[r]) + __expf(lg2t1 - l2a[r]));
                    pv[r] = p; rs1 += p;
                }
                uint2 dd; dd.x = pack2bf(pv[0], pv[1]); dd.y = pack2bf(pv[2], pv[3]);
                *(uint2*)&bufPw[(16 + l15) * LDP + s0] = dd;
            }
        }
    }
    rs0 += __shfl_xor(rs0, 16); rs0 += __shfl_xor(rs0, 32);
    rs1 += __shfl_xor(rs1, 16); rs1 += __shfl_xor(rs1, 32);
    float osc0 = mt0 / fmaxf(a1t0 * d1_0 + a2t0 * d2_0 + rs0, 1e-6f);
    float osc1 = mt1 / fmaxf(a1t1 * d1_1 + a2t1 * d2_1 + rs1, 1e-6f);

    // ---- QH: acc += (a_st*phiQ) . H_st, hf batched 16-deep ----
    f32x4 acc_o0[8], acc_o1[8];
#pragma unroll
    for (int m = 0; m < 8; ++m) { acc_o0[m] = zero4(); acc_o1[m] = zero4(); }
#pragma unroll
    for (int st = 0; st < 2; ++st) {
        const unsigned short* Hp = Cws + ((size_t)(st * B_ + b) * NC_ + c) * (D_ * D_);
        float sc0 = st ? a2t0 : a1t0;
        float sc1 = st ? a2t1 : a1t1;
#pragma unroll
        for (int ks2 = 0; ks2 < 2; ++ks2) {
            bf16x8 hf[16];
#pragma unroll
            for (int kq = 0; kq < 2; ++kq)
#pragma unroll
                for (int m = 0; m < 8; ++m)
                    hf[kq * 8 + m] = *(const bf16x8*)&Hp[(size_t)(((m * 4 + ks2 * 2 + kq) * 64 + lane) * 8)];
#pragma unroll
            for (int kq = 0; kq < 2; ++kq) {
                int ks = ks2 * 2 + kq;
                bf16x8 qs0, qs1;
#pragma unroll
                for (int j = 0; j < 8; ++j) {
                    qs0[j] = (short)bf16r(fbf((unsigned short)qf0[ks][j]) * sc0);
                    qs1[j] = (short)bf16r(fbf((unsigned short)qf1[ks][j]) * sc1);
                }
#pragma unroll
                for (int m = 0; m < 8; ++m) {
                    acc_o0[m] = __builtin_amdgcn_mfma_f32_16x16x32_bf16(hf[kq * 8 + m], qs0, acc_o0[m], 0, 0, 0);
                    acc_o1[m] = __builtin_amdgcn_mfma_f32_16x16x32_bf16(hf[kq * 8 + m], qs1, acc_o1[m], 0, 0, 0);
                }
            }
        }
    }

    // ---- PV: acc += Vt @ P^T, vf batched 8-deep ----
#pragma unroll
    for (int ks = 0; ks < 4; ++ks) {
        bf16x8 vf[8];
#pragma unroll
        for (int m = 0; m < 8; ++m)
            vf[m] = *(const bf16x8*)&VtT[cb + (size_t)(((m * 4 + ks) * 64 + lane) * 8)];
        bf16x8 pf1 = *(const bf16x8*)&bufPw[(16 + l15) * LDP + ks * 32 + lg4 * 8];
        if (ks < 2) {
            bf16x8 pf0 = *(const bf16x8*)&bufPw[l15 * LDP + ks * 32 + lg4 * 8];
#pragma unroll
            for (int m = 0; m < 8; ++m)
                acc_o0[m] = __builtin_amdgcn_mfma_f32_16x16x32_bf16(vf[m], pf0, acc_o0[m], 0, 0, 0);
        }
#pragma unroll
        for (int m = 0; m < 8; ++m)
            acc_o1[m] = __builtin_amdgcn_mfma_f32_16x16x32_bf16(vf[m], pf1, acc_o1[m], 0, 0, 0);
    }

    // ---- store ----
#pragma unroll
    for (int m = 0; m < 8; ++m) {
        float4 o0, o1;
        o0.x = acc_o0[m][0] * osc0; o0.y = acc_o0[m][1] * osc0;
        o0.z = acc_o0[m][2] * osc0; o0.w = acc_o0[m][3] * osc0;
        o1.x = acc_o1[m][0] * osc1; o1.y = acc_o1[m][1] * osc1;
        o1.z = acc_o1[m][2] * osc1; o1.w = acc_o1[m][3] * osc1;
        *(float4*)&out[gt0 * D_ + m * 16 + lg4 * 4] = o0;
        *(float4*)&out[gt1 * D_ + m * 16 + lg4 * 4] = o1;
    }
}

extern "C" void kernel_launch(void* const* d_in, const int* in_sizes, int n_in,
                              void* d_out, int out_size, void* d_ws, size_t ws_size,
                              hipStream_t stream) {
    const float* q    = (const float*)d_in[0];
    const float* k    = (const float*)d_in[1];
    const float* v    = (const float*)d_in[2];
    const float* beta = (const float*)d_in[3];
    const float* mask = (const float*)d_in[4];
    const float* bb1  = (const float*)d_in[5];
    const float* bb2  = (const float*)d_in[6];
    float* out = (float*)d_out;

    size_t n_lg = (size_t)B_ * T_;                       // 65536
    size_t n_z  = (size_t)2 * B_ * NC_ * D_;             // 131072
    size_t n_C  = (size_t)2 * B_ * NC_ * D_ * D_;        // 16777216 bf16
    size_t n_kt = (size_t)B_ * T_ * D_;                  // 8388608 bf16
    size_t need = (2 * n_lg + n_z) * sizeof(float) + (n_C + 2 * n_kt) * sizeof(unsigned short);
    if (ws_size < need) return;

    float* lg1 = (float*)d_ws;
    float* lg2 = lg1 + n_lg;
    float* zc  = lg2 + n_lg;
    unsigned short* Cws   = (unsigned short*)(zc + n_z);
    unsigned short* phiKT = Cws + n_C;
    unsigned short* VtT   = phiKT + n_kt;

    kA<<<CH_, 256, 0, stream>>>(beta, bb1, bb2, k, v, mask, lg1, lg2, phiKT, VtT, Cws, zc);
    k2f<<<528, 256, 0, stream>>>(Cws, zc, lg1, lg2);
    k3_v6<<<CH_, 256, 0, stream>>>(q, mask, lg1, lg2, phiKT, VtT, Cws, zc, out);
}